// Round 8
// baseline (3854.655 us; speedup 1.0000x reference)
//
#include <hip/hip_runtime.h>
#include <hip/hip_bf16.h>
#include <math.h>

#define BB   32
#define SS   128
#define DD   64
#define HTT  256
#define TEE  1024
#define NTHR 512
#define STEPF 0.1f

typedef __attribute__((ext_vector_type(8))) short short8b;   // 8 x bf16
typedef __attribute__((ext_vector_type(4))) float float4v;   // MFMA C/D

__device__ __forceinline__ unsigned short f2b(float f) {     // f32 -> bf16 RNE
    union { float f; unsigned int u; } x; x.f = f;
    unsigned int u = x.u + 0x7FFFu + ((x.u >> 16) & 1u);
    return (unsigned short)(u >> 16);
}
__device__ __forceinline__ unsigned int pack2(float lo, float hi) {
    return (unsigned int)f2b(lo) | ((unsigned int)f2b(hi) << 16);
}

// ---------------------------------------------------------------------------
// Kernel 0: pack weights into MFMA B-fragment order, bf16 (unchanged).
// frag f: lane l elem e -> B[k = ks*32 + (l>>4)*8 + e][col = nt*16 + (l&15)]
// qkv f=0..23 (nt*2+ks) | o 24..31 | fc 32..63 | pr 64..95 (nt*8+ks)
// ---------------------------------------------------------------------------
__global__ void pack_frags(const float* __restrict__ w_qkv,
                           const float* __restrict__ w_o,
                           const float* __restrict__ w_fc,
                           const float* __restrict__ w_pr,
                           unsigned short* __restrict__ frags) {
    const int tile = blockIdx.x;
    const int t = threadIdx.x;          // 512
    const int lane = t >> 3, e = t & 7;
    const float* W; int N, nt, ks;
    if (tile < 24)      { W = w_qkv; N = 192; int s = tile;      nt = s >> 1; ks = s & 1; }
    else if (tile < 32) { W = w_o;   N = 64;  int s = tile - 24; nt = s >> 1; ks = s & 1; }
    else if (tile < 64) { W = w_fc;  N = 256; int s = tile - 32; nt = s >> 1; ks = s & 1; }
    else                { W = w_pr;  N = 64;  int s = tile - 64; nt = s >> 3; ks = s & 7; }
    const int k   = ks * 32 + (lane >> 4) * 8 + e;
    const int col = nt * 16 + (lane & 15);
    frags[tile * 512 + lane * 8 + e] = f2b(W[k * N + col]);
}

// ---------------------------------------------------------------------------
// Kernel 1: precompute temb[t][d] (unchanged).
// ---------------------------------------------------------------------------
__global__ void temb_precompute(const int* __restrict__ nloops_p,
                                const float* __restrict__ t_w1,
                                const float* __restrict__ t_b1,
                                const float* __restrict__ t_w2,
                                const float* __restrict__ t_b2,
                                float* __restrict__ tembBuf) {
    const int t = blockIdx.x;
    const int nl = nloops_p[0];
    if (t >= nl) return;

    __shared__ float te_s[HTT];
    __shared__ float h1[TEE];
    const int tid = threadIdx.x;
    const float tf = (float)t;

    {
        int fi = (tid < 128) ? tid : (tid - 128);
        float freq = expf(-9.210340371976184f * (float)fi * (1.0f / 128.0f));
        float arg = tf * freq;
        te_s[tid] = (tid < 128) ? cosf(arg) : sinf(arg);
    }
    __syncthreads();

    for (int j = tid; j < TEE; j += 256) {
        float acc = t_b1[j];
        for (int i = 0; i < HTT; ++i)
            acc = fmaf(te_s[i], t_w1[i * TEE + j], acc);
        h1[j] = acc / (1.0f + expf(-acc));   // silu
    }
    __syncthreads();

    {
        const int d = tid >> 2, part = tid & 3;
        float acc = 0.0f;
        for (int j = part; j < TEE; j += 4)
            acc = fmaf(h1[j], t_w2[j * DD + d], acc);
        acc += __shfl_xor(acc, 1);
        acc += __shfl_xor(acc, 2);
        if (part == 0) tembBuf[t * DD + d] = acc + t_b2[d];
    }
}

__device__ __forceinline__ float gelu_tanh(float u) {
    float z = 0.7978845608028654f * (u + 0.044715f * u * u * u);
    float e = __expf(2.0f * z);
    float th = 1.0f - 2.0f / (e + 1.0f);
    return 0.5f * u * (1.0f + th);
}

// ---------------------------------------------------------------------------
// Kernel 2: looped transformer. 1 block (512 thr / 8 waves) per batch.
// x state in REGISTERS (16 f32/lane, mapping row=wv*16+4fq+r col=16nt+fr).
// 3 barriers/iter: after C (QKV->pool), after D (attn->hsb), pool-guard in H.
// LDS: hsb 16K | pool 65K (qb/kb/vtb aliased by msb) | pstage 9K | wfrag 32K
//    = 124928 B
// ---------------------------------------------------------------------------
__global__ __launch_bounds__(NTHR, 2)
void looped_tf(const int* __restrict__ idx,
               const int* __restrict__ nloops_p,
               const float* __restrict__ wte,
               const float* __restrict__ wpe,
               const float* __restrict__ ln1_g, const float* __restrict__ ln1_b,
               const float* __restrict__ b_qkv,
               const float* __restrict__ b_o,
               const float* __restrict__ ln2_g, const float* __restrict__ ln2_b,
               const float* __restrict__ b_fc,
               const float* __restrict__ b_pr,
               const float* __restrict__ lnf_g, const float* __restrict__ lnf_b,
               const float* __restrict__ tembBuf,
               const unsigned short* __restrict__ frags,
               float* __restrict__ out) {
    __shared__ __align__(16) unsigned short hsb[SS * DD];      // 16384B
    __shared__ __align__(16) unsigned char pool[66560];
    __shared__ __align__(16) unsigned char pstage[8 * 1152];   // [wave][16 rows][72B]
    __shared__ __align__(16) unsigned short wfrag[16384];      // frags 0..31 parked

    unsigned char* qb  = pool;                    // [4][q 0..127][d]*48B, swz (q>>3)
    unsigned char* kb  = pool + 24576;            // [4][p 0..127][d]*48B, p=(k>>1)+64*(k&1)
    unsigned char* vtb = pool + 49152;            // [4][d 0..15][k]*272B (V^T)
    unsigned short* msb = (unsigned short*)pool;  // [128] rows x 512B, swz (row&7)

    const unsigned short* fcF = frags + 32 * 512;
    const unsigned short* prF = frags + 64 * 512;

    const int b   = blockIdx.x;
    const int tid = threadIdx.x;
    const int nl  = nloops_p[0];
    const int wv  = tid >> 6;
    const int ln  = tid & 63;
    const int fr  = ln & 15;
    const int fq  = ln >> 4;
    const int rowbase = wv * 16 + fq * 4;

    // ---- park qkv+o frags (32KB) in LDS ----
    for (int i = tid; i < 2048; i += NTHR)
        ((int4*)wfrag)[i] = ((const int4*)frags)[i];

    // ---- preload per-lane biases / LN params ----
    float bqkvr[12], bor[4], bprr[4];
    float l1g[4], l1b[4], l2g[4], l2b[4], lfg[4], lfb[4];
#pragma unroll
    for (int nt = 0; nt < 12; ++nt) bqkvr[nt] = b_qkv[nt * 16 + fr];
#pragma unroll
    for (int nc = 0; nc < 4; ++nc) {
        int c = nc * 16 + fr;
        bor[nc] = b_o[c];  bprr[nc] = b_pr[c];
        l1g[nc] = ln1_g[c]; l1b[nc] = ln1_b[c];
        l2g[nc] = ln2_g[c]; l2b[nc] = ln2_b[c];
        lfg[nc] = lnf_g[c]; lfb[nc] = lnf_b[c];
    }

    // ---- x state in registers: xr[r][nc] at (rowbase+r, nc*16+fr) ----
    float xr[4][4];
#pragma unroll
    for (int r = 0; r < 4; ++r) {
        int row = rowbase + r;
        int iv = idx[b * SS + row];
#pragma unroll
        for (int nc = 0; nc < 4; ++nc)
            xr[r][nc] = wte[iv * 64 + nc * 16 + fr] + wpe[row * 64 + nc * 16 + fr];
    }

    __syncthreads();   // wfrag parked

    // fused LN over register state -> hsb (bf16, swizzled)
    auto ln_fused = [&](const float* g4, const float* b4) {
        float s1[4], s2[4];
#pragma unroll
        for (int r = 0; r < 4; ++r) {
            s1[r] = xr[r][0] + xr[r][1] + xr[r][2] + xr[r][3];
            s2[r] = xr[r][0]*xr[r][0] + xr[r][1]*xr[r][1]
                  + xr[r][2]*xr[r][2] + xr[r][3]*xr[r][3];
        }
#pragma unroll
        for (int m = 1; m <= 8; m <<= 1) {
#pragma unroll
            for (int r = 0; r < 4; ++r) {
                s1[r] += __shfl_xor(s1[r], m);
                s2[r] += __shfl_xor(s2[r], m);
            }
        }
#pragma unroll
        for (int r = 0; r < 4; ++r) {
            float mu = s1[r] * (1.0f / 64.0f);
            float var = s2[r] * (1.0f / 64.0f) - mu * mu;
            float rs = rsqrtf(var + 1e-5f);
            int row = rowbase + r;
            int swz = (row & 7) << 4;
#pragma unroll
            for (int nc = 0; nc < 4; ++nc) {
                float h = (xr[r][nc] - mu) * rs * g4[nc] + b4[nc];
                int byte = (row * 128 + (nc * 16 + fr) * 2) ^ swz;
                *(unsigned short*)((char*)hsb + byte) = f2b(h);
            }
        }
    };

    // A-frag from swizzled bf16 LDS tile (wave rows wv*16+fr)
    auto load_afrag = [&](const unsigned short* buf, int rstrideB, int kstep) -> short8b {
        int row = wv * 16 + fr;
        int byte = row * rstrideB + kstep * 64 + fq * 16;
        return *(const short8b*)((const char*)buf + (byte ^ ((row & 7) << 4)));
    };

    // ---- prelude: x += temb[0]; LN1 -> hsb ----
    if (nl > 0) {
#pragma unroll
        for (int nc = 0; nc < 4; ++nc) {
            float tv = tembBuf[nc * 16 + fr];
#pragma unroll
            for (int r = 0; r < 4; ++r) xr[r][nc] += tv;
        }
        ln_fused(l1g, l1b);
    }

    for (int t = 0; t < nl; ++t) {
        // ---- C: qkv = h @ w_qkv + b (MFMA) -> qb/kb(permuted)/vtb ----
        {
            short8b a0 = load_afrag(hsb, 128, 0);
            short8b a1 = load_afrag(hsb, 128, 1);
            float4v acc[12];
#pragma unroll
            for (int nt = 0; nt < 12; ++nt) acc[nt] = (float4v)0.0f;
#pragma unroll
            for (int nt = 0; nt < 12; ++nt) {
                short8b b0 = *(const short8b*)(&wfrag[(nt * 2 + 0) * 512 + ln * 8]);
                short8b b1 = *(const short8b*)(&wfrag[(nt * 2 + 1) * 512 + ln * 8]);
                acc[nt] = __builtin_amdgcn_mfma_f32_16x16x32_bf16(a0, b0, acc[nt], 0, 0, 0);
                acc[nt] = __builtin_amdgcn_mfma_f32_16x16x32_bf16(a1, b1, acc[nt], 0, 0, 0);
            }
#pragma unroll
            for (int nt = 0; nt < 12; ++nt) {
#pragma unroll
                for (int r = 0; r < 4; ++r) {
                    int row = rowbase + r;
                    unsigned short bv = f2b(acc[nt][r] + bqkvr[nt]);
                    if (nt < 4) {                       // Q
                        int byte = nt * 6144 + row * 48 + fr * 2;
                        byte ^= ((row >> 3) & 7) << 4;
                        *(unsigned short*)(qb + byte) = bv;
                    } else if (nt < 8) {                // K (even/odd permuted rows)
                        int h = nt - 4;
                        int p = (row >> 1) + 64 * (row & 1);
                        *(unsigned short*)(kb + h * 6144 + p * 48 + fr * 2) = bv;
                    } else {                            // V^T
                        int h = nt - 8;
                        *(unsigned short*)(vtb + h * 4352 + fr * 272 + row * 2) = bv;
                    }
                }
            }
        }
        __syncthreads();

        // ---- D: flash attention via MFMA (strided q = wv+8j; max-free exp) ----
        {
            short8b aq[4];
            {
                bool lo = (ln < 32);
#pragma unroll
                for (int h = 0; h < 4; ++h) {
                    short8b z = (short8b)(short)0;
                    if (lo) {
                        int q = wv + 8 * fr;
                        int byte = h * 6144 + q * 48 + (fq & 1) * 16;
                        byte ^= (fr & 7) << 4;          // (q>>3)&7 == fr&7
                        z = *(const short8b*)(qb + byte);
                    }
                    aq[h] = z;
                }
            }
            short8b onesb;
#pragma unroll
            for (int e = 0; e < 8; ++e) onesb[e] = (short)0x3F80;  // bf16 1.0

            float4v o[4], lac[4];
#pragma unroll
            for (int h = 0; h < 4; ++h) { o[h] = (float4v)0.0f; lac[h] = (float4v)0.0f; }

            unsigned char* pst = pstage + wv * 1152;    // [16 rows][72B]

            for (int ktp = 0; ktp < 4; ++ktp) {
#pragma unroll
                for (int h = 0; h < 4; ++h) {
                    // even/odd k tiles -> lane holds adjacent k pair
                    short8b bk0 = (short8b)(short)0, bk1 = (short8b)(short)0;
                    if (ln < 32) {
                        int kbase = h * 6144 + (fq & 1) * 16;
                        bk0 = *(const short8b*)(kb + kbase + (ktp * 16 + fr) * 48);
                        bk1 = *(const short8b*)(kb + kbase + (64 + ktp * 16 + fr) * 48);
                    }
                    float4v s0 = __builtin_amdgcn_mfma_f32_16x16x32_bf16(aq[h], bk0, (float4v)0.0f, 0, 0, 0);
                    float4v s1 = __builtin_amdgcn_mfma_f32_16x16x32_bf16(aq[h], bk1, (float4v)0.0f, 0, 0, 0);
#pragma unroll
                    for (int r = 0; r < 4; ++r) {
                        int j = 4 * fq + r;
                        int q = wv + 8 * j;
                        int k0 = ktp * 32 + 2 * fr;
                        float p0 = (k0     <= q) ? __expf(s0[r] * 0.25f) : 0.0f;
                        float p1 = (k0 + 1 <= q) ? __expf(s1[r] * 0.25f) : 0.0f;
                        *(unsigned int*)(pst + j * 72 + fr * 4) = pack2(p0, p1);
                    }
                    short8b ap = *(const short8b*)(pst + fr * 72 + fq * 16);
                    short8b bv = *(const short8b*)(vtb + h * 4352 + fr * 272 + ktp * 64 + fq * 16);
                    o[h]   = __builtin_amdgcn_mfma_f32_16x16x32_bf16(ap, bv, o[h], 0, 0, 0);
                    lac[h] = __builtin_amdgcn_mfma_f32_16x16x32_bf16(ap, onesb, lac[h], 0, 0, 0);
                }
            }
#pragma unroll
            for (int h = 0; h < 4; ++h) {
#pragma unroll
                for (int r = 0; r < 4; ++r) {
                    int j = 4 * fq + r;
                    int q = wv + 8 * j;
                    float val = o[h][r] / lac[h][r];
                    int byte = (q * 128 + (h * 16 + fr) * 2) ^ ((q & 7) << 4);
                    *(unsigned short*)((char*)hsb + byte) = f2b(val);
                }
            }
        }
        __syncthreads();

        // ---- E + LN2 fused: x += STEP*(a@w_o + b_o); LN2 -> hsb ----
        {
            short8b a0 = load_afrag(hsb, 128, 0);
            short8b a1 = load_afrag(hsb, 128, 1);
            float4v acc[4];
#pragma unroll
            for (int nt = 0; nt < 4; ++nt) acc[nt] = (float4v)0.0f;
#pragma unroll
            for (int nt = 0; nt < 4; ++nt) {
                short8b b0 = *(const short8b*)(&wfrag[(24 + nt * 2 + 0) * 512 + ln * 8]);
                short8b b1 = *(const short8b*)(&wfrag[(24 + nt * 2 + 1) * 512 + ln * 8]);
                acc[nt] = __builtin_amdgcn_mfma_f32_16x16x32_bf16(a0, b0, acc[nt], 0, 0, 0);
                acc[nt] = __builtin_amdgcn_mfma_f32_16x16x32_bf16(a1, b1, acc[nt], 0, 0, 0);
            }
#pragma unroll
            for (int nt = 0; nt < 4; ++nt)
#pragma unroll
                for (int r = 0; r < 4; ++r)
                    xr[r][nt] += STEPF * (acc[nt][r] + bor[nt]);
            ln_fused(l2g, l2b);
        }
        // no barrier: hsb rows are wave-partitioned

        // ---- G: m = gelu(h2 @ w_fc + b_fc) -> msb (aliases pool) ----
        {
            short8b a0 = load_afrag(hsb, 128, 0);
            short8b a1 = load_afrag(hsb, 128, 1);
            float4v acc[16];
#pragma unroll
            for (int nt = 0; nt < 16; ++nt) acc[nt] = (float4v)0.0f;
#pragma unroll
            for (int half = 0; half < 2; ++half) {
                short8b buf[16];
#pragma unroll
                for (int i = 0; i < 16; ++i)
                    buf[i] = *(const short8b*)(fcF + ((half * 16 + i) * 64 + ln) * 8);
#pragma unroll
                for (int i = 0; i < 8; ++i) {
                    int nt = half * 8 + i;
                    acc[nt] = __builtin_amdgcn_mfma_f32_16x16x32_bf16(a0, buf[2*i],   acc[nt], 0, 0, 0);
                    acc[nt] = __builtin_amdgcn_mfma_f32_16x16x32_bf16(a1, buf[2*i+1], acc[nt], 0, 0, 0);
                }
            }
            char* base = (char*)msb;
#pragma unroll
            for (int nt = 0; nt < 16; ++nt) {
                const float bias = b_fc[nt * 16 + fr];
#pragma unroll
                for (int r = 0; r < 4; ++r) {
                    int row = rowbase + r;
                    int byte = row * 512 + (nt * 16 + fr) * 2;
                    *(unsigned short*)(base + (byte ^ ((row & 7) << 4))) =
                        f2b(gelu_tanh(acc[nt][r] + bias));
                }
            }
        }
        // no barrier: msb rows wave-partitioned

        // ---- H: x += STEP*(m @ w_pr + b_pr); + temb(t+1); LN1 -> hsb ----
        {
            short8b am[8];
#pragma unroll
            for (int ks = 0; ks < 8; ++ks)
                am[ks] = load_afrag(msb, 512, ks);
            // prefetch pr frags (global) before the pool-guard barrier
            short8b buf0[16], buf1[16];
#pragma unroll
            for (int i = 0; i < 16; ++i)
                buf0[i] = *(const short8b*)(prF + (i * 64 + ln) * 8);
#pragma unroll
            for (int i = 0; i < 16; ++i)
                buf1[i] = *(const short8b*)(prF + ((16 + i) * 64 + ln) * 8);
            __syncthreads();   // all msb reads done before next C overwrites pool

            float4v acc[4];
#pragma unroll
            for (int nt = 0; nt < 4; ++nt) acc[nt] = (float4v)0.0f;
#pragma unroll
            for (int i = 0; i < 16; ++i) {
                int nt = i >> 3;
                acc[nt] = __builtin_amdgcn_mfma_f32_16x16x32_bf16(am[i & 7], buf0[i], acc[nt], 0, 0, 0);
            }
#pragma unroll
            for (int i = 0; i < 16; ++i) {
                int nt = 2 + (i >> 3);
                acc[nt] = __builtin_amdgcn_mfma_f32_16x16x32_bf16(am[i & 7], buf1[i], acc[nt], 0, 0, 0);
            }
#pragma unroll
            for (int nt = 0; nt < 4; ++nt)
#pragma unroll
                for (int r = 0; r < 4; ++r)
                    xr[r][nt] += STEPF * (acc[nt][r] + bprr[nt]);

            if (t + 1 < nl) {
#pragma unroll
                for (int nc = 0; nc < 4; ++nc) {
                    float tv = tembBuf[(t + 1) * 64 + nc * 16 + fr];
#pragma unroll
                    for (int r = 0; r < 4; ++r) xr[r][nc] += tv;
                }
                ln_fused(l1g, l1b);
            }
        }
        // no barrier: next C reads only own-wave hsb rows + wfrag
    }

    // ---- final LN -> out (f32, from registers) ----
    {
        float s1[4], s2[4];
#pragma unroll
        for (int r = 0; r < 4; ++r) {
            s1[r] = xr[r][0] + xr[r][1] + xr[r][2] + xr[r][3];
            s2[r] = xr[r][0]*xr[r][0] + xr[r][1]*xr[r][1]
                  + xr[r][2]*xr[r][2] + xr[r][3]*xr[r][3];
        }
#pragma unroll
        for (int m = 1; m <= 8; m <<= 1) {
#pragma unroll
            for (int r = 0; r < 4; ++r) {
                s1[r] += __shfl_xor(s1[r], m);
                s2[r] += __shfl_xor(s2[r], m);
            }
        }
#pragma unroll
        for (int r = 0; r < 4; ++r) {
            float mu = s1[r] * (1.0f / 64.0f);
            float var = s2[r] * (1.0f / 64.0f) - mu * mu;
            float rs = rsqrtf(var + 1e-5f);
            int row = rowbase + r;
#pragma unroll
            for (int nc = 0; nc < 4; ++nc) {
                float val = (xr[r][nc] - mu) * rs * lfg[nc] + lfb[nc];
                out[b * SS * DD + row * 64 + nc * 16 + fr] = val;
            }
        }
    }
}

// ---------------------------------------------------------------------------
extern "C" void kernel_launch(void* const* d_in, const int* in_sizes, int n_in,
                              void* d_out, int out_size, void* d_ws, size_t ws_size,
                              hipStream_t stream) {
    const int*   idx    = (const int*)  d_in[0];
    const int*   nloops = (const int*)  d_in[1];
    const float* wte    = (const float*)d_in[2];
    const float* wpe    = (const float*)d_in[3];
    const float* t_w1   = (const float*)d_in[4];
    const float* t_b1   = (const float*)d_in[5];
    const float* t_w2   = (const float*)d_in[6];
    const float* t_b2   = (const float*)d_in[7];
    const float* ln1_g  = (const float*)d_in[8];
    const float* ln1_b  = (const float*)d_in[9];
    const float* w_qkv  = (const float*)d_in[10];
    const float* b_qkv  = (const float*)d_in[11];
    const float* w_o    = (const float*)d_in[12];
    const float* b_o    = (const float*)d_in[13];
    const float* ln2_g  = (const float*)d_in[14];
    const float* ln2_b  = (const float*)d_in[15];
    const float* w_fc   = (const float*)d_in[16];
    const float* b_fc   = (const float*)d_in[17];
    const float* w_pr   = (const float*)d_in[18];
    const float* b_pr   = (const float*)d_in[19];
    const float* lnf_g  = (const float*)d_in[20];
    const float* lnf_b  = (const float*)d_in[21];

    float* tembBuf = (float*)d_ws;                                   // 32 KB
    unsigned short* frags = (unsigned short*)((char*)d_ws + 32768);  // 96 KB

    pack_frags<<<96, 512, 0, stream>>>(w_qkv, w_o, w_fc, w_pr, frags);
    temb_precompute<<<128, 256, 0, stream>>>(nloops, t_w1, t_b1, t_w2, t_b2, tembBuf);
    looped_tf<<<BB, NTHR, 0, stream>>>(idx, nloops, wte, wpe, ln1_g, ln1_b,
                                       b_qkv, b_o, ln2_g, ln2_b,
                                       b_fc, b_pr, lnf_g, lnf_b,
                                       tembBuf, frags, (float*)d_out);
}

// Round 9
// 3503.698 us; speedup vs baseline: 1.1002x; 1.1002x over previous
//
#include <hip/hip_runtime.h>
#include <hip/hip_bf16.h>
#include <math.h>

#define BB   32
#define SS   128
#define DD   64
#define HTT  256
#define TEE  1024
#define NTHR 1024
#define STEPF 0.1f

typedef __attribute__((ext_vector_type(8))) short short8b;   // 8 x bf16
typedef __attribute__((ext_vector_type(4))) float float4v;   // MFMA C/D

__device__ __forceinline__ unsigned short f2b(float f) {     // f32 -> bf16 RNE
    union { float f; unsigned int u; } x; x.f = f;
    unsigned int u = x.u + 0x7FFFu + ((x.u >> 16) & 1u);
    return (unsigned short)(u >> 16);
}
__device__ __forceinline__ unsigned int pack2(float lo, float hi) {
    return (unsigned int)f2b(lo) | ((unsigned int)f2b(hi) << 16);
}

// ---------------------------------------------------------------------------
// Kernel 0: pack weights into MFMA B-fragment order, bf16 (unchanged).
// frag f: lane l elem e -> B[k = ks*32 + (l>>4)*8 + e][col = nt*16 + (l&15)]
// qkv f=0..23 (nt*2+ks) | o 24..31 | fc 32..63 | pr 64..95 (nt*8+ks)
// ---------------------------------------------------------------------------
__global__ void pack_frags(const float* __restrict__ w_qkv,
                           const float* __restrict__ w_o,
                           const float* __restrict__ w_fc,
                           const float* __restrict__ w_pr,
                           unsigned short* __restrict__ frags) {
    const int tile = blockIdx.x;
    const int t = threadIdx.x;          // 512
    const int lane = t >> 3, e = t & 7;
    const float* W; int N, nt, ks;
    if (tile < 24)      { W = w_qkv; N = 192; int s = tile;      nt = s >> 1; ks = s & 1; }
    else if (tile < 32) { W = w_o;   N = 64;  int s = tile - 24; nt = s >> 1; ks = s & 1; }
    else if (tile < 64) { W = w_fc;  N = 256; int s = tile - 32; nt = s >> 1; ks = s & 1; }
    else                { W = w_pr;  N = 64;  int s = tile - 64; nt = s >> 3; ks = s & 7; }
    const int k   = ks * 32 + (lane >> 4) * 8 + e;
    const int col = nt * 16 + (lane & 15);
    frags[tile * 512 + lane * 8 + e] = f2b(W[k * N + col]);
}

// ---------------------------------------------------------------------------
// Kernel 1: precompute temb[t][d] (unchanged).
// ---------------------------------------------------------------------------
__global__ void temb_precompute(const int* __restrict__ nloops_p,
                                const float* __restrict__ t_w1,
                                const float* __restrict__ t_b1,
                                const float* __restrict__ t_w2,
                                const float* __restrict__ t_b2,
                                float* __restrict__ tembBuf) {
    const int t = blockIdx.x;
    const int nl = nloops_p[0];
    if (t >= nl) return;

    __shared__ float te_s[HTT];
    __shared__ float h1[TEE];
    const int tid = threadIdx.x;
    const float tf = (float)t;

    {
        int fi = (tid < 128) ? tid : (tid - 128);
        float freq = expf(-9.210340371976184f * (float)fi * (1.0f / 128.0f));
        float arg = tf * freq;
        te_s[tid] = (tid < 128) ? cosf(arg) : sinf(arg);
    }
    __syncthreads();

    for (int j = tid; j < TEE; j += 256) {
        float acc = t_b1[j];
        for (int i = 0; i < HTT; ++i)
            acc = fmaf(te_s[i], t_w1[i * TEE + j], acc);
        h1[j] = acc / (1.0f + expf(-acc));   // silu
    }
    __syncthreads();

    {
        const int d = tid >> 2, part = tid & 3;
        float acc = 0.0f;
        for (int j = part; j < TEE; j += 4)
            acc = fmaf(h1[j], t_w2[j * DD + d], acc);
        acc += __shfl_xor(acc, 1);
        acc += __shfl_xor(acc, 2);
        if (part == 0) tembBuf[t * DD + d] = acc + t_b2[d];
    }
}

__device__ __forceinline__ float gelu_tanh(float u) {
    float z = 0.7978845608028654f * (u + 0.044715f * u * u * u);
    float e = __expf(2.0f * z);
    float th = 1.0f - 2.0f / (e + 1.0f);
    return 0.5f * u * (1.0f + th);
}

// ---------------------------------------------------------------------------
// Kernel 2: looped transformer. 1 block (1024 thr / 16 waves) per batch.
// wave = (wg = wv&7 row-group of 16 rows, wh = wv>>3 column-half).
// x state in registers: xr[4][2] at (row = wg*16+fq*4+r, col = (wh*2+nc)*16+fr).
// LDS: hsb 16K | pool 65K (qb/kb/vtb aliased by msb) | pstage 36K (per wavexhead)
//      | wfrag 32K | lnred 2K  = 154624 B
// ---------------------------------------------------------------------------
__global__ __launch_bounds__(NTHR, 4)
void looped_tf(const int* __restrict__ idx,
               const int* __restrict__ nloops_p,
               const float* __restrict__ wte,
               const float* __restrict__ wpe,
               const float* __restrict__ ln1_g, const float* __restrict__ ln1_b,
               const float* __restrict__ b_qkv,
               const float* __restrict__ b_o,
               const float* __restrict__ ln2_g, const float* __restrict__ ln2_b,
               const float* __restrict__ b_fc,
               const float* __restrict__ b_pr,
               const float* __restrict__ lnf_g, const float* __restrict__ lnf_b,
               const float* __restrict__ tembBuf,
               const unsigned short* __restrict__ frags,
               float* __restrict__ out) {
    __shared__ __align__(16) unsigned short hsb[SS * DD];      // 16384B
    __shared__ __align__(16) unsigned char pool[66560];
    __shared__ __align__(16) unsigned char pstage[16 * 2 * 1152]; // [wave][head][16][72B]
    __shared__ __align__(16) unsigned short wfrag[16384];      // frags 0..31 parked
    __shared__ __align__(16) float2 lnred[SS][2];              // LN partial (s1,s2)

    unsigned char* qb  = pool;                    // [4][q][d]*48B, swz (q>>3)
    unsigned char* kb  = pool + 24576;            // [4][p][d]*48B, p=(k>>1)+64*(k&1)
    unsigned char* vtb = pool + 49152;            // [4][d][k]*272B (V^T)
    unsigned short* msb = (unsigned short*)pool;  // [128] rows x 512B, swz (row&7)

    const unsigned short* fcF = frags + 32 * 512;
    const unsigned short* prF = frags + 64 * 512;

    const int b   = blockIdx.x;
    const int tid = threadIdx.x;
    const int nl  = nloops_p[0];
    const int wv  = tid >> 6;
    const int wg  = wv & 7;            // row group
    const int wh  = wv >> 3;           // column half
    const int ln  = tid & 63;
    const int fr  = ln & 15;
    const int fq  = ln >> 4;
    const int rowbase = wg * 16 + fq * 4;

    // ---- park qkv+o frags (32KB) in LDS ----
    for (int i = tid; i < 2048; i += NTHR)
        ((int4*)wfrag)[i] = ((const int4*)frags)[i];

    // ---- preload per-lane biases / LN params (this wave's columns) ----
    float bqkvr[6], bfcr[8], bor[2], bprr[2];
    float l1g[2], l1b[2], l2g[2], l2b[2], lfg[2], lfb[2];
#pragma unroll
    for (int i = 0; i < 6; ++i) bqkvr[i] = b_qkv[(wh * 6 + i) * 16 + fr];
#pragma unroll
    for (int i = 0; i < 8; ++i) bfcr[i] = b_fc[(wh * 8 + i) * 16 + fr];
#pragma unroll
    for (int nc = 0; nc < 2; ++nc) {
        int c = (wh * 2 + nc) * 16 + fr;
        bor[nc] = b_o[c];  bprr[nc] = b_pr[c];
        l1g[nc] = ln1_g[c]; l1b[nc] = ln1_b[c];
        l2g[nc] = ln2_g[c]; l2b[nc] = ln2_b[c];
        lfg[nc] = lnf_g[c]; lfb[nc] = lnf_b[c];
    }

    // ---- x state in registers ----
    float xr[4][2];
#pragma unroll
    for (int r = 0; r < 4; ++r) {
        int row = rowbase + r;
        int iv = idx[b * SS + row];
#pragma unroll
        for (int nc = 0; nc < 2; ++nc) {
            int c = (wh * 2 + nc) * 16 + fr;
            xr[r][nc] = wte[iv * 64 + c] + wpe[row * 64 + c];
        }
    }
    __syncthreads();   // wfrag parked

    // LN over register state -> hsb (bf16, swizzled); 2-wave combine via lnred
    auto ln_fused = [&](const float* g2, const float* b2) {
        float s1[4], s2[4];
#pragma unroll
        for (int r = 0; r < 4; ++r) {
            s1[r] = xr[r][0] + xr[r][1];
            s2[r] = xr[r][0]*xr[r][0] + xr[r][1]*xr[r][1];
        }
#pragma unroll
        for (int m = 1; m <= 8; m <<= 1) {
#pragma unroll
            for (int r = 0; r < 4; ++r) {
                s1[r] += __shfl_xor(s1[r], m);
                s2[r] += __shfl_xor(s2[r], m);
            }
        }
        if (fr == 0) {
#pragma unroll
            for (int r = 0; r < 4; ++r) {
                float2 v; v.x = s1[r]; v.y = s2[r];
                lnred[rowbase + r][wh] = v;
            }
        }
        __syncthreads();
#pragma unroll
        for (int r = 0; r < 4; ++r) {
            float2 oth = lnred[rowbase + r][wh ^ 1];
            float t1 = s1[r] + oth.x, t2 = s2[r] + oth.y;
            float mu = t1 * (1.0f / 64.0f);
            float var = t2 * (1.0f / 64.0f) - mu * mu;
            float rs = rsqrtf(var + 1e-5f);
            int row = rowbase + r;
            int swz = (row & 7) << 4;
#pragma unroll
            for (int nc = 0; nc < 2; ++nc) {
                float h = (xr[r][nc] - mu) * rs * g2[nc] + b2[nc];
                int byte = (row * 128 + ((wh * 2 + nc) * 16 + fr) * 2) ^ swz;
                *(unsigned short*)((char*)hsb + byte) = f2b(h);
            }
        }
        __syncthreads();
    };

    // A-frag from swizzled bf16 LDS tile (rows wg*16+fr)
    auto load_afrag = [&](const unsigned short* buf, int rstrideB, int kstep) -> short8b {
        int row = wg * 16 + fr;
        int byte = row * rstrideB + kstep * 64 + fq * 16;
        return *(const short8b*)((const char*)buf + (byte ^ ((row & 7) << 4)));
    };

    // ---- prelude: x += temb[0]; LN1 -> hsb ----
    if (nl > 0) {
#pragma unroll
        for (int nc = 0; nc < 2; ++nc) {
            float tv = tembBuf[(wh * 2 + nc) * 16 + fr];
#pragma unroll
            for (int r = 0; r < 4; ++r) xr[r][nc] += tv;
        }
        ln_fused(l1g, l1b);
    }

    for (int t = 0; t < nl; ++t) {
        // ---- C: qkv = h @ w_qkv + b (MFMA, nt split 6/6) -> qb/kb/vtb ----
        {
            short8b a0 = load_afrag(hsb, 128, 0);
            short8b a1 = load_afrag(hsb, 128, 1);
            float4v acc[6];
#pragma unroll
            for (int i = 0; i < 6; ++i) acc[i] = (float4v)0.0f;
#pragma unroll
            for (int i = 0; i < 6; ++i) {
                int nt = wh * 6 + i;
                short8b b0 = *(const short8b*)(&wfrag[(nt * 2 + 0) * 512 + ln * 8]);
                short8b b1 = *(const short8b*)(&wfrag[(nt * 2 + 1) * 512 + ln * 8]);
                acc[i] = __builtin_amdgcn_mfma_f32_16x16x32_bf16(a0, b0, acc[i], 0, 0, 0);
                acc[i] = __builtin_amdgcn_mfma_f32_16x16x32_bf16(a1, b1, acc[i], 0, 0, 0);
            }
#pragma unroll
            for (int i = 0; i < 6; ++i) {
                int nt = wh * 6 + i;
#pragma unroll
                for (int r = 0; r < 4; ++r) {
                    int row = rowbase + r;
                    unsigned short bv = f2b(acc[i][r] + bqkvr[i]);
                    if (nt < 4) {                       // Q (heads 0-3)
                        int byte = nt * 6144 + row * 48 + fr * 2;
                        byte ^= ((row >> 3) & 7) << 4;
                        *(unsigned short*)(qb + byte) = bv;
                    } else if (nt < 8) {                // K (even/odd permuted)
                        int h = nt - 4;
                        int p = (row >> 1) + 64 * (row & 1);
                        *(unsigned short*)(kb + h * 6144 + p * 48 + fr * 2) = bv;
                    } else {                            // V^T
                        int h = nt - 8;
                        *(unsigned short*)(vtb + h * 4352 + fr * 272 + row * 2) = bv;
                    }
                }
            }
        }
        __syncthreads();

        // ---- D: flash attention via MFMA; heads split 2/2; per-head pstage ----
        {
            const bool lo = (ln < 32);
            short8b aq[2];
#pragma unroll
            for (int hh = 0; hh < 2; ++hh) {
                int h = wh * 2 + hh;
                short8b z = (short8b)(short)0;
                if (lo) {
                    int q = wg + 8 * fr;
                    int byte = h * 6144 + q * 48 + (fq & 1) * 16;
                    byte ^= (fr & 7) << 4;              // (q>>3)&7 == fr&7
                    z = *(const short8b*)(qb + byte);
                }
                aq[hh] = z;
            }
            short8b onesb;
#pragma unroll
            for (int e = 0; e < 8; ++e) onesb[e] = (short)0x3F80;  // bf16 1.0

            float4v o[2], lac[2];
#pragma unroll
            for (int hh = 0; hh < 2; ++hh) { o[hh] = (float4v)0.0f; lac[hh] = (float4v)0.0f; }

            for (int ktp = 0; ktp < 4; ++ktp) {
#pragma unroll
                for (int hh = 0; hh < 2; ++hh) {
                    int h = wh * 2 + hh;
                    unsigned char* pst = pstage + (wv * 2 + hh) * 1152;
                    short8b bk0 = (short8b)(short)0, bk1 = (short8b)(short)0;
                    if (lo) {
                        int kbase = h * 6144 + (fq & 1) * 16;
                        bk0 = *(const short8b*)(kb + kbase + (ktp * 16 + fr) * 48);
                        bk1 = *(const short8b*)(kb + kbase + (64 + ktp * 16 + fr) * 48);
                    }
                    float4v s0 = __builtin_amdgcn_mfma_f32_16x16x32_bf16(aq[hh], bk0, (float4v)0.0f, 0, 0, 0);
                    float4v s1 = __builtin_amdgcn_mfma_f32_16x16x32_bf16(aq[hh], bk1, (float4v)0.0f, 0, 0, 0);
#pragma unroll
                    for (int r = 0; r < 4; ++r) {
                        int j = 4 * fq + r;
                        int q = wg + 8 * j;
                        int k0 = ktp * 32 + 2 * fr;
                        float p0 = (k0     <= q) ? __expf(s0[r] * 0.25f) : 0.0f;
                        float p1 = (k0 + 1 <= q) ? __expf(s1[r] * 0.25f) : 0.0f;
                        *(unsigned int*)(pst + j * 72 + fr * 4) = pack2(p0, p1);
                    }
                    short8b ap = *(const short8b*)(pst + fr * 72 + fq * 16);
                    short8b bv = *(const short8b*)(vtb + h * 4352 + fr * 272 + ktp * 64 + fq * 16);
                    o[hh]   = __builtin_amdgcn_mfma_f32_16x16x32_bf16(ap, bv, o[hh], 0, 0, 0);
                    lac[hh] = __builtin_amdgcn_mfma_f32_16x16x32_bf16(ap, onesb, lac[hh], 0, 0, 0);
                }
            }
#pragma unroll
            for (int hh = 0; hh < 2; ++hh) {
                int h = wh * 2 + hh;
#pragma unroll
                for (int r = 0; r < 4; ++r) {
                    int j = 4 * fq + r;
                    int q = wg + 8 * j;
                    float val = o[hh][r] / lac[hh][r];
                    int byte = (q * 128 + (h * 16 + fr) * 2) ^ ((q & 7) << 4);
                    *(unsigned short*)((char*)hsb + byte) = f2b(val);
                }
            }
        }
        __syncthreads();

        // ---- E + LN2: x += STEP*(a@w_o + b_o); LN2 -> hsb ----
        {
            short8b a0 = load_afrag(hsb, 128, 0);
            short8b a1 = load_afrag(hsb, 128, 1);
            float4v acc[2];
#pragma unroll
            for (int i = 0; i < 2; ++i) acc[i] = (float4v)0.0f;
#pragma unroll
            for (int i = 0; i < 2; ++i) {
                int nt = wh * 2 + i;
                short8b b0 = *(const short8b*)(&wfrag[(24 + nt * 2 + 0) * 512 + ln * 8]);
                short8b b1 = *(const short8b*)(&wfrag[(24 + nt * 2 + 1) * 512 + ln * 8]);
                acc[i] = __builtin_amdgcn_mfma_f32_16x16x32_bf16(a0, b0, acc[i], 0, 0, 0);
                acc[i] = __builtin_amdgcn_mfma_f32_16x16x32_bf16(a1, b1, acc[i], 0, 0, 0);
            }
#pragma unroll
            for (int i = 0; i < 2; ++i)
#pragma unroll
                for (int r = 0; r < 4; ++r)
                    xr[r][i] += STEPF * (acc[i][r] + bor[i]);
            ln_fused(l2g, l2b);   // includes 2 barriers; hsb ready after
        }

        // ---- G: m = gelu(h2 @ w_fc + b_fc) -> msb (nt split 8/8) ----
        {
            short8b a0 = load_afrag(hsb, 128, 0);
            short8b a1 = load_afrag(hsb, 128, 1);
            float4v acc[8];
#pragma unroll
            for (int i = 0; i < 8; ++i) acc[i] = (float4v)0.0f;
#pragma unroll
            for (int i = 0; i < 8; ++i) {
                int nt = wh * 8 + i;
                short8b b0 = *(const short8b*)(fcF + ((nt * 2 + 0) * 64 + ln) * 8);
                short8b b1 = *(const short8b*)(fcF + ((nt * 2 + 1) * 64 + ln) * 8);
                acc[i] = __builtin_amdgcn_mfma_f32_16x16x32_bf16(a0, b0, acc[i], 0, 0, 0);
                acc[i] = __builtin_amdgcn_mfma_f32_16x16x32_bf16(a1, b1, acc[i], 0, 0, 0);
            }
            char* base = (char*)msb;
#pragma unroll
            for (int i = 0; i < 8; ++i) {
                int nt = wh * 8 + i;
#pragma unroll
                for (int r = 0; r < 4; ++r) {
                    int row = rowbase + r;
                    int byte = row * 512 + (nt * 16 + fr) * 2;
                    *(unsigned short*)(base + (byte ^ ((row & 7) << 4))) =
                        f2b(gelu_tanh(acc[i][r] + bfcr[i]));
                }
            }
        }
        __syncthreads();   // msb full (both halves) before H reads

        // ---- H: x += STEP*(m @ w_pr + b_pr); + temb(t+1); LN1 -> hsb ----
        {
            short8b am[8];
#pragma unroll
            for (int ks = 0; ks < 8; ++ks)
                am[ks] = load_afrag(msb, 512, ks);
            float4v acc[2];
#pragma unroll
            for (int i = 0; i < 2; ++i) acc[i] = (float4v)0.0f;
#pragma unroll
            for (int i = 0; i < 2; ++i) {
                int nt = wh * 2 + i;
#pragma unroll
                for (int ks = 0; ks < 8; ++ks) {
                    short8b bp = *(const short8b*)(prF + ((nt * 8 + ks) * 64 + ln) * 8);
                    acc[i] = __builtin_amdgcn_mfma_f32_16x16x32_bf16(am[ks], bp, acc[i], 0, 0, 0);
                }
            }
#pragma unroll
            for (int i = 0; i < 2; ++i)
#pragma unroll
                for (int r = 0; r < 4; ++r)
                    xr[r][i] += STEPF * (acc[i][r] + bprr[i]);

            if (t + 1 < nl) {
#pragma unroll
                for (int nc = 0; nc < 2; ++nc) {
                    float tv = tembBuf[(t + 1) * 64 + (wh * 2 + nc) * 16 + fr];
#pragma unroll
                    for (int r = 0; r < 4; ++r) xr[r][nc] += tv;
                }
                ln_fused(l1g, l1b);   // barriers also guard pool vs next C
            }
        }
    }

    // ---- final LN -> out (f32, from registers; 2-wave combine) ----
    {
        float s1[4], s2[4];
#pragma unroll
        for (int r = 0; r < 4; ++r) {
            s1[r] = xr[r][0] + xr[r][1];
            s2[r] = xr[r][0]*xr[r][0] + xr[r][1]*xr[r][1];
        }
#pragma unroll
        for (int m = 1; m <= 8; m <<= 1) {
#pragma unroll
            for (int r = 0; r < 4; ++r) {
                s1[r] += __shfl_xor(s1[r], m);
                s2[r] += __shfl_xor(s2[r], m);
            }
        }
        if (fr == 0) {
#pragma unroll
            for (int r = 0; r < 4; ++r) {
                float2 v; v.x = s1[r]; v.y = s2[r];
                lnred[rowbase + r][wh] = v;
            }
        }
        __syncthreads();
#pragma unroll
        for (int r = 0; r < 4; ++r) {
            float2 oth = lnred[rowbase + r][wh ^ 1];
            float t1 = s1[r] + oth.x, t2 = s2[r] + oth.y;
            float mu = t1 * (1.0f / 64.0f);
            float var = t2 * (1.0f / 64.0f) - mu * mu;
            float rs = rsqrtf(var + 1e-5f);
            int row = rowbase + r;
#pragma unroll
            for (int nc = 0; nc < 2; ++nc) {
                int c = (wh * 2 + nc) * 16 + fr;
                out[b * SS * DD + row * 64 + c] = (xr[r][nc] - mu) * rs * lfg[nc] + lfb[nc];
            }
        }
    }
}

// ---------------------------------------------------------------------------
extern "C" void kernel_launch(void* const* d_in, const int* in_sizes, int n_in,
                              void* d_out, int out_size, void* d_ws, size_t ws_size,
                              hipStream_t stream) {
    const int*   idx    = (const int*)  d_in[0];
    const int*   nloops = (const int*)  d_in[1];
    const float* wte    = (const float*)d_in[2];
    const float* wpe    = (const float*)d_in[3];
    const float* t_w1   = (const float*)d_in[4];
    const float* t_b1   = (const float*)d_in[5];
    const float* t_w2   = (const float*)d_in[6];
    const float* t_b2   = (const float*)d_in[7];
    const float* ln1_g  = (const float*)d_in[8];
    const float* ln1_b  = (const float*)d_in[9];
    const float* w_qkv  = (const float*)d_in[10];
    const float* b_qkv  = (const float*)d_in[11];
    const float* w_o    = (const float*)d_in[12];
    const float* b_o    = (const float*)d_in[13];
    const float* ln2_g  = (const float*)d_in[14];
    const float* ln2_b  = (const float*)d_in[15];
    const float* w_fc   = (const float*)d_in[16];
    const float* b_fc   = (const float*)d_in[17];
    const float* w_pr   = (const float*)d_in[18];
    const float* b_pr   = (const float*)d_in[19];
    const float* lnf_g  = (const float*)d_in[20];
    const float* lnf_b  = (const float*)d_in[21];

    float* tembBuf = (float*)d_ws;                                   // 32 KB
    unsigned short* frags = (unsigned short*)((char*)d_ws + 32768);  // 96 KB

    pack_frags<<<96, 512, 0, stream>>>(w_qkv, w_o, w_fc, w_pr, frags);
    temb_precompute<<<128, 256, 0, stream>>>(nloops, t_w1, t_b1, t_w2, t_b2, tembBuf);
    looped_tf<<<BB, NTHR, 0, stream>>>(idx, nloops, wte, wpe, ln1_g, ln1_b,
                                       b_qkv, b_o, ln2_g, ln2_b,
                                       b_fc, b_pr, lnf_g, lnf_b,
                                       tembBuf, frags, (float*)d_out);
}

// Round 10
// 3238.821 us; speedup vs baseline: 1.1901x; 1.0818x over previous
//
#include <hip/hip_runtime.h>
#include <hip/hip_bf16.h>
#include <math.h>

#define BB   32
#define SS   128
#define DD   64
#define HTT  256
#define TEE  1024
#define NTHR 1024
#define STEPF 0.1f

typedef __attribute__((ext_vector_type(8))) short short8b;   // 8 x bf16
typedef __attribute__((ext_vector_type(4))) float float4v;   // MFMA C/D

__device__ __forceinline__ unsigned short f2b(float f) {     // f32 -> bf16 RNE
    union { float f; unsigned int u; } x; x.f = f;
    unsigned int u = x.u + 0x7FFFu + ((x.u >> 16) & 1u);
    return (unsigned short)(u >> 16);
}
__device__ __forceinline__ unsigned int cvtpk2(float lo, float hi) {  // HW RNE pack
    unsigned int r;
    asm("v_cvt_pk_bf16_f32 %0, %1, %2" : "=v"(r) : "v"(lo), "v"(hi));
    return r;
}

// ---------------------------------------------------------------------------
// Kernel 0: pack weights into MFMA B-fragment order, bf16 (unchanged).
// frag f: lane l elem e -> B[k = ks*32 + (l>>4)*8 + e][col = nt*16 + (l&15)]
// qkv f=0..23 (nt*2+ks) | o 24..31 | fc 32..63 | pr 64..95 (nt*8+ks)
// ---------------------------------------------------------------------------
__global__ void pack_frags(const float* __restrict__ w_qkv,
                           const float* __restrict__ w_o,
                           const float* __restrict__ w_fc,
                           const float* __restrict__ w_pr,
                           unsigned short* __restrict__ frags) {
    const int tile = blockIdx.x;
    const int t = threadIdx.x;          // 512
    const int lane = t >> 3, e = t & 7;
    const float* W; int N, nt, ks;
    if (tile < 24)      { W = w_qkv; N = 192; int s = tile;      nt = s >> 1; ks = s & 1; }
    else if (tile < 32) { W = w_o;   N = 64;  int s = tile - 24; nt = s >> 1; ks = s & 1; }
    else if (tile < 64) { W = w_fc;  N = 256; int s = tile - 32; nt = s >> 1; ks = s & 1; }
    else                { W = w_pr;  N = 64;  int s = tile - 64; nt = s >> 3; ks = s & 7; }
    const int k   = ks * 32 + (lane >> 4) * 8 + e;
    const int col = nt * 16 + (lane & 15);
    frags[tile * 512 + lane * 8 + e] = f2b(W[k * N + col]);
}

// ---------------------------------------------------------------------------
// Kernel 1: precompute temb[t][d] (unchanged).
// ---------------------------------------------------------------------------
__global__ void temb_precompute(const int* __restrict__ nloops_p,
                                const float* __restrict__ t_w1,
                                const float* __restrict__ t_b1,
                                const float* __restrict__ t_w2,
                                const float* __restrict__ t_b2,
                                float* __restrict__ tembBuf) {
    const int t = blockIdx.x;
    const int nl = nloops_p[0];
    if (t >= nl) return;

    __shared__ float te_s[HTT];
    __shared__ float h1[TEE];
    const int tid = threadIdx.x;
    const float tf = (float)t;

    {
        int fi = (tid < 128) ? tid : (tid - 128);
        float freq = expf(-9.210340371976184f * (float)fi * (1.0f / 128.0f));
        float arg = tf * freq;
        te_s[tid] = (tid < 128) ? cosf(arg) : sinf(arg);
    }
    __syncthreads();

    for (int j = tid; j < TEE; j += 256) {
        float acc = t_b1[j];
        for (int i = 0; i < HTT; ++i)
            acc = fmaf(te_s[i], t_w1[i * TEE + j], acc);
        h1[j] = acc / (1.0f + expf(-acc));   // silu
    }
    __syncthreads();

    {
        const int d = tid >> 2, part = tid & 3;
        float acc = 0.0f;
        for (int j = part; j < TEE; j += 4)
            acc = fmaf(h1[j], t_w2[j * DD + d], acc);
        acc += __shfl_xor(acc, 1);
        acc += __shfl_xor(acc, 2);
        if (part == 0) tembBuf[t * DD + d] = acc + t_b2[d];
    }
}

__device__ __forceinline__ float gelu_tanh(float u) {
    float z = 0.7978845608028654f * (u + 0.044715f * u * u * u);
    float e = __expf(2.0f * z);
    float th = 1.0f - 2.0f / (e + 1.0f);
    return 0.5f * u * (1.0f + th);
}

// ---------------------------------------------------------------------------
// Kernel 2: looped transformer. 1 block (1024 thr / 16 waves) per batch.
// wave = (wg = wv&7 row-group of 16 rows, wh = wv>>3 column-half).
// waves_per_eu(4,4): target exactly 4 waves/EU -> VGPR budget 128 (stop the
// 64-VGPR remat squeeze seen in round 9).
// LDS: hsb 16K | pool 65K | pstage 36K | wfrag 32K | lnred 2K = 154624 B
// ---------------------------------------------------------------------------
__global__ __launch_bounds__(NTHR, 4) __attribute__((amdgpu_waves_per_eu(4, 4)))
void looped_tf(const int* __restrict__ idx,
               const int* __restrict__ nloops_p,
               const float* __restrict__ wte,
               const float* __restrict__ wpe,
               const float* __restrict__ ln1_g, const float* __restrict__ ln1_b,
               const float* __restrict__ b_qkv,
               const float* __restrict__ b_o,
               const float* __restrict__ ln2_g, const float* __restrict__ ln2_b,
               const float* __restrict__ b_fc,
               const float* __restrict__ b_pr,
               const float* __restrict__ lnf_g, const float* __restrict__ lnf_b,
               const float* __restrict__ tembBuf,
               const unsigned short* __restrict__ frags,
               float* __restrict__ out) {
    __shared__ __align__(16) unsigned short hsb[SS * DD];      // 16384B
    __shared__ __align__(16) unsigned char pool[66560];
    __shared__ __align__(16) unsigned char pstage[16 * 2 * 1152]; // [wave][head][16][72B]
    __shared__ __align__(16) unsigned short wfrag[16384];      // frags 0..31 parked
    __shared__ __align__(16) float2 lnred[SS][2];              // LN partial (s1,s2)

    unsigned char* qb  = pool;                    // [4][q][d]*48B, swz (q>>3)
    unsigned char* kb  = pool + 24576;            // [4][p][d]*48B, p=(k>>1)+64*(k&1)
    unsigned char* vtb = pool + 49152;            // [4][d][k]*272B (V^T)
    unsigned short* msb = (unsigned short*)pool;  // [128] rows x 512B, swz (row&7)

    const unsigned short* fcF = frags + 32 * 512;
    const unsigned short* prF = frags + 64 * 512;

    const int b   = blockIdx.x;
    const int tid = threadIdx.x;
    const int nl  = nloops_p[0];
    const int wv  = tid >> 6;
    const int wg  = wv & 7;            // row group
    const int wh  = wv >> 3;           // column half
    const int ln  = tid & 63;
    const int fr  = ln & 15;
    const int fq  = ln >> 4;
    const int rowbase = wg * 16 + fq * 4;

    // ---- park qkv+o frags (32KB) in LDS ----
    for (int i = tid; i < 2048; i += NTHR)
        ((int4*)wfrag)[i] = ((const int4*)frags)[i];

    // ---- preload per-lane biases / LN params (this wave's columns) ----
    float bqkvr[6], bfcr[8], bor[2], bprr[2];
    float l1g[2], l1b[2], l2g[2], l2b[2], lfg[2], lfb[2];
#pragma unroll
    for (int i = 0; i < 6; ++i) bqkvr[i] = b_qkv[(wh * 6 + i) * 16 + fr];
#pragma unroll
    for (int i = 0; i < 8; ++i) bfcr[i] = b_fc[(wh * 8 + i) * 16 + fr];
#pragma unroll
    for (int nc = 0; nc < 2; ++nc) {
        int c = (wh * 2 + nc) * 16 + fr;
        bor[nc] = b_o[c];  bprr[nc] = b_pr[c];
        l1g[nc] = ln1_g[c]; l1b[nc] = ln1_b[c];
        l2g[nc] = ln2_g[c]; l2b[nc] = ln2_b[c];
        lfg[nc] = lnf_g[c]; lfb[nc] = lnf_b[c];
    }

    // ---- x state in registers ----
    float xr[4][2];
#pragma unroll
    for (int r = 0; r < 4; ++r) {
        int row = rowbase + r;
        int iv = idx[b * SS + row];
#pragma unroll
        for (int nc = 0; nc < 2; ++nc) {
            int c = (wh * 2 + nc) * 16 + fr;
            xr[r][nc] = wte[iv * 64 + c] + wpe[row * 64 + c];
        }
    }
    __syncthreads();   // wfrag parked

    // LN over register state -> hsb (bf16, swizzled); 2-wave combine via lnred
    auto ln_fused = [&](const float* g2, const float* b2) {
        float s1[4], s2[4];
#pragma unroll
        for (int r = 0; r < 4; ++r) {
            s1[r] = xr[r][0] + xr[r][1];
            s2[r] = xr[r][0]*xr[r][0] + xr[r][1]*xr[r][1];
        }
#pragma unroll
        for (int m = 1; m <= 8; m <<= 1) {
#pragma unroll
            for (int r = 0; r < 4; ++r) {
                s1[r] += __shfl_xor(s1[r], m);
                s2[r] += __shfl_xor(s2[r], m);
            }
        }
        if (fr == 0) {
#pragma unroll
            for (int r = 0; r < 4; ++r) {
                float2 v; v.x = s1[r]; v.y = s2[r];
                lnred[rowbase + r][wh] = v;
            }
        }
        __syncthreads();
#pragma unroll
        for (int r = 0; r < 4; ++r) {
            float2 oth = lnred[rowbase + r][wh ^ 1];
            float t1 = s1[r] + oth.x, t2 = s2[r] + oth.y;
            float mu = t1 * (1.0f / 64.0f);
            float var = t2 * (1.0f / 64.0f) - mu * mu;
            float rs = rsqrtf(var + 1e-5f);
            int row = rowbase + r;
            int swz = (row & 7) << 4;
#pragma unroll
            for (int nc = 0; nc < 2; ++nc) {
                float h = (xr[r][nc] - mu) * rs * g2[nc] + b2[nc];
                int byte = (row * 128 + ((wh * 2 + nc) * 16 + fr) * 2) ^ swz;
                *(unsigned short*)((char*)hsb + byte) = f2b(h);
            }
        }
        __syncthreads();
    };

    // A-frag from swizzled bf16 LDS tile (rows wg*16+fr)
    auto load_afrag = [&](const unsigned short* buf, int rstrideB, int kstep) -> short8b {
        int row = wg * 16 + fr;
        int byte = row * rstrideB + kstep * 64 + fq * 16;
        return *(const short8b*)((const char*)buf + (byte ^ ((row & 7) << 4)));
    };

    // ---- prelude: x += temb[0]; LN1 -> hsb ----
    if (nl > 0) {
#pragma unroll
        for (int nc = 0; nc < 2; ++nc) {
            float tv = tembBuf[(wh * 2 + nc) * 16 + fr];
#pragma unroll
            for (int r = 0; r < 4; ++r) xr[r][nc] += tv;
        }
        ln_fused(l1g, l1b);
    }

    for (int t = 0; t < nl; ++t) {
        // ---- C: qkv = h @ w_qkv + b (MFMA, nt split 6/6) -> qb/kb/vtb ----
        // Q (nt<4) pre-scaled by 0.25 (softmax scale folded in)
        {
            short8b a0 = load_afrag(hsb, 128, 0);
            short8b a1 = load_afrag(hsb, 128, 1);
            float4v acc[6];
#pragma unroll
            for (int i = 0; i < 6; ++i) acc[i] = (float4v)0.0f;
#pragma unroll
            for (int i = 0; i < 6; ++i) {
                int nt = wh * 6 + i;
                short8b b0 = *(const short8b*)(&wfrag[(nt * 2 + 0) * 512 + ln * 8]);
                short8b b1 = *(const short8b*)(&wfrag[(nt * 2 + 1) * 512 + ln * 8]);
                acc[i] = __builtin_amdgcn_mfma_f32_16x16x32_bf16(a0, b0, acc[i], 0, 0, 0);
                acc[i] = __builtin_amdgcn_mfma_f32_16x16x32_bf16(a1, b1, acc[i], 0, 0, 0);
            }
#pragma unroll
            for (int i = 0; i < 6; ++i) {
                int nt = wh * 6 + i;
#pragma unroll
                for (int r = 0; r < 4; ++r) {
                    int row = rowbase + r;
                    float v = acc[i][r] + bqkvr[i];
                    if (nt < 4) {                       // Q (heads 0-3), 0.25x
                        unsigned short bv = f2b(v * 0.25f);
                        int byte = nt * 6144 + row * 48 + fr * 2;
                        byte ^= ((row >> 3) & 7) << 4;
                        *(unsigned short*)(qb + byte) = bv;
                    } else if (nt < 8) {                // K (even/odd permuted)
                        int h = nt - 4;
                        int p = (row >> 1) + 64 * (row & 1);
                        *(unsigned short*)(kb + h * 6144 + p * 48 + fr * 2) = f2b(v);
                    } else {                            // V^T
                        int h = nt - 8;
                        *(unsigned short*)(vtb + h * 4352 + fr * 272 + row * 2) = f2b(v);
                    }
                }
            }
        }
        __syncthreads();

        // ---- D: flash attention via MFMA; heads split 2/2; fissioned ktp body ----
        {
            const bool lo = (ln < 32);
            short8b aq[2];
#pragma unroll
            for (int hh = 0; hh < 2; ++hh) {
                int h = wh * 2 + hh;
                short8b z = (short8b)(short)0;
                if (lo) {
                    int q = wg + 8 * fr;
                    int byte = h * 6144 + q * 48 + (fq & 1) * 16;
                    byte ^= (fr & 7) << 4;              // (q>>3)&7 == fr&7
                    z = *(const short8b*)(qb + byte);
                }
                aq[hh] = z;
            }
            short8b onesb;
#pragma unroll
            for (int e = 0; e < 8; ++e) onesb[e] = (short)0x3F80;  // bf16 1.0

            float4v o[2], lac[2];
#pragma unroll
            for (int hh = 0; hh < 2; ++hh) { o[hh] = (float4v)0.0f; lac[hh] = (float4v)0.0f; }

            for (int ktp = 0; ktp < 4; ++ktp) {
                // (1) QK for both heads
                float4v s0h[2], s1h[2];
#pragma unroll
                for (int hh = 0; hh < 2; ++hh) {
                    int h = wh * 2 + hh;
                    short8b bk0 = (short8b)(short)0, bk1 = (short8b)(short)0;
                    if (lo) {
                        int kbase = h * 6144 + (fq & 1) * 16;
                        bk0 = *(const short8b*)(kb + kbase + (ktp * 16 + fr) * 48);
                        bk1 = *(const short8b*)(kb + kbase + (64 + ktp * 16 + fr) * 48);
                    }
                    s0h[hh] = __builtin_amdgcn_mfma_f32_16x16x32_bf16(aq[hh], bk0, (float4v)0.0f, 0, 0, 0);
                    s1h[hh] = __builtin_amdgcn_mfma_f32_16x16x32_bf16(aq[hh], bk1, (float4v)0.0f, 0, 0, 0);
                }
                // (2) exp + pack both heads (Q pre-scaled; HW cvt_pk)
#pragma unroll
                for (int hh = 0; hh < 2; ++hh) {
                    unsigned char* pst = pstage + (wv * 2 + hh) * 1152;
#pragma unroll
                    for (int r = 0; r < 4; ++r) {
                        int j = 4 * fq + r;
                        int q = wg + 8 * j;
                        int k0 = ktp * 32 + 2 * fr;
                        float p0 = (k0     <= q) ? __expf(s0h[hh][r]) : 0.0f;
                        float p1 = (k0 + 1 <= q) ? __expf(s1h[hh][r]) : 0.0f;
                        *(unsigned int*)(pst + j * 72 + fr * 4) = cvtpk2(p0, p1);
                    }
                }
                // (3) PV for both heads (single lgkmcnt covers both pstage writes)
#pragma unroll
                for (int hh = 0; hh < 2; ++hh) {
                    int h = wh * 2 + hh;
                    unsigned char* pst = pstage + (wv * 2 + hh) * 1152;
                    short8b ap = *(const short8b*)(pst + fr * 72 + fq * 16);
                    short8b bv = *(const short8b*)(vtb + h * 4352 + fr * 272 + ktp * 64 + fq * 16);
                    o[hh]   = __builtin_amdgcn_mfma_f32_16x16x32_bf16(ap, bv, o[hh], 0, 0, 0);
                    lac[hh] = __builtin_amdgcn_mfma_f32_16x16x32_bf16(ap, onesb, lac[hh], 0, 0, 0);
                }
            }
#pragma unroll
            for (int hh = 0; hh < 2; ++hh) {
                int h = wh * 2 + hh;
#pragma unroll
                for (int r = 0; r < 4; ++r) {
                    int j = 4 * fq + r;
                    int q = wg + 8 * j;
                    float val = o[hh][r] / lac[hh][r];
                    int byte = (q * 128 + (h * 16 + fr) * 2) ^ ((q & 7) << 4);
                    *(unsigned short*)((char*)hsb + byte) = f2b(val);
                }
            }
        }
        __syncthreads();

        // ---- E + LN2: x += STEP*(a@w_o + b_o); LN2 -> hsb ----
        {
            short8b a0 = load_afrag(hsb, 128, 0);
            short8b a1 = load_afrag(hsb, 128, 1);
            float4v acc[2];
#pragma unroll
            for (int i = 0; i < 2; ++i) acc[i] = (float4v)0.0f;
#pragma unroll
            for (int i = 0; i < 2; ++i) {
                int nt = wh * 2 + i;
                short8b b0 = *(const short8b*)(&wfrag[(24 + nt * 2 + 0) * 512 + ln * 8]);
                short8b b1 = *(const short8b*)(&wfrag[(24 + nt * 2 + 1) * 512 + ln * 8]);
                acc[i] = __builtin_amdgcn_mfma_f32_16x16x32_bf16(a0, b0, acc[i], 0, 0, 0);
                acc[i] = __builtin_amdgcn_mfma_f32_16x16x32_bf16(a1, b1, acc[i], 0, 0, 0);
            }
#pragma unroll
            for (int i = 0; i < 2; ++i)
#pragma unroll
                for (int r = 0; r < 4; ++r)
                    xr[r][i] += STEPF * (acc[i][r] + bor[i]);
            ln_fused(l2g, l2b);   // includes 2 barriers; hsb ready after
        }

        // ---- G: m = gelu(h2 @ w_fc + b_fc) -> msb (nt split 8/8) ----
        {
            short8b a0 = load_afrag(hsb, 128, 0);
            short8b a1 = load_afrag(hsb, 128, 1);
            float4v acc[8];
#pragma unroll
            for (int i = 0; i < 8; ++i) acc[i] = (float4v)0.0f;
#pragma unroll
            for (int i = 0; i < 8; ++i) {
                int nt = wh * 8 + i;
                short8b b0 = *(const short8b*)(fcF + ((nt * 2 + 0) * 64 + ln) * 8);
                short8b b1 = *(const short8b*)(fcF + ((nt * 2 + 1) * 64 + ln) * 8);
                acc[i] = __builtin_amdgcn_mfma_f32_16x16x32_bf16(a0, b0, acc[i], 0, 0, 0);
                acc[i] = __builtin_amdgcn_mfma_f32_16x16x32_bf16(a1, b1, acc[i], 0, 0, 0);
            }
            char* base = (char*)msb;
#pragma unroll
            for (int i = 0; i < 8; ++i) {
                int nt = wh * 8 + i;
#pragma unroll
                for (int r = 0; r < 4; ++r) {
                    int row = rowbase + r;
                    int byte = row * 512 + (nt * 16 + fr) * 2;
                    *(unsigned short*)(base + (byte ^ ((row & 7) << 4))) =
                        f2b(gelu_tanh(acc[i][r] + bfcr[i]));
                }
            }
        }
        __syncthreads();   // msb full (both halves) before H reads

        // ---- H: x += STEP*(m @ w_pr + b_pr); + temb(t+1); LN1 -> hsb ----
        {
            short8b am[8];
#pragma unroll
            for (int ks = 0; ks < 8; ++ks)
                am[ks] = load_afrag(msb, 512, ks);
            float4v acc[2];
#pragma unroll
            for (int i = 0; i < 2; ++i) acc[i] = (float4v)0.0f;
#pragma unroll
            for (int i = 0; i < 2; ++i) {
                int nt = wh * 2 + i;
#pragma unroll
                for (int ks = 0; ks < 8; ++ks) {
                    short8b bp = *(const short8b*)(prF + ((nt * 8 + ks) * 64 + ln) * 8);
                    acc[i] = __builtin_amdgcn_mfma_f32_16x16x32_bf16(am[ks], bp, acc[i], 0, 0, 0);
                }
            }
#pragma unroll
            for (int i = 0; i < 2; ++i)
#pragma unroll
                for (int r = 0; r < 4; ++r)
                    xr[r][i] += STEPF * (acc[i][r] + bprr[i]);

            if (t + 1 < nl) {
#pragma unroll
                for (int nc = 0; nc < 2; ++nc) {
                    float tv = tembBuf[(t + 1) * 64 + (wh * 2 + nc) * 16 + fr];
#pragma unroll
                    for (int r = 0; r < 4; ++r) xr[r][nc] += tv;
                }
                ln_fused(l1g, l1b);   // barriers also guard pool vs next C
            }
        }
    }

    // ---- final LN -> out (f32, from registers; 2-wave combine) ----
    {
        float s1[4], s2[4];
#pragma unroll
        for (int r = 0; r < 4; ++r) {
            s1[r] = xr[r][0] + xr[r][1];
            s2[r] = xr[r][0]*xr[r][0] + xr[r][1]*xr[r][1];
        }
#pragma unroll
        for (int m = 1; m <= 8; m <<= 1) {
#pragma unroll
            for (int r = 0; r < 4; ++r) {
                s1[r] += __shfl_xor(s1[r], m);
                s2[r] += __shfl_xor(s2[r], m);
            }
        }
        if (fr == 0) {
#pragma unroll
            for (int r = 0; r < 4; ++r) {
                float2 v; v.x = s1[r]; v.y = s2[r];
                lnred[rowbase + r][wh] = v;
            }
        }
        __syncthreads();
#pragma unroll
        for (int r = 0; r < 4; ++r) {
            float2 oth = lnred[rowbase + r][wh ^ 1];
            float t1 = s1[r] + oth.x, t2 = s2[r] + oth.y;
            float mu = t1 * (1.0f / 64.0f);
            float var = t2 * (1.0f / 64.0f) - mu * mu;
            float rs = rsqrtf(var + 1e-5f);
            int row = rowbase + r;
#pragma unroll
            for (int nc = 0; nc < 2; ++nc) {
                int c = (wh * 2 + nc) * 16 + fr;
                out[b * SS * DD + row * 64 + c] = (xr[r][nc] - mu) * rs * lfg[nc] + lfb[nc];
            }
        }
    }
}

// ---------------------------------------------------------------------------
extern "C" void kernel_launch(void* const* d_in, const int* in_sizes, int n_in,
                              void* d_out, int out_size, void* d_ws, size_t ws_size,
                              hipStream_t stream) {
    const int*   idx    = (const int*)  d_in[0];
    const int*   nloops = (const int*)  d_in[1];
    const float* wte    = (const float*)d_in[2];
    const float* wpe    = (const float*)d_in[3];
    const float* t_w1   = (const float*)d_in[4];
    const float* t_b1   = (const float*)d_in[5];
    const float* t_w2   = (const float*)d_in[6];
    const float* t_b2   = (const float*)d_in[7];
    const float* ln1_g  = (const float*)d_in[8];
    const float* ln1_b  = (const float*)d_in[9];
    const float* w_qkv  = (const float*)d_in[10];
    const float* b_qkv  = (const float*)d_in[11];
    const float* w_o    = (const float*)d_in[12];
    const float* b_o    = (const float*)d_in[13];
    const float* ln2_g  = (const float*)d_in[14];
    const float* ln2_b  = (const float*)d_in[15];
    const float* w_fc   = (const float*)d_in[16];
    const float* b_fc   = (const float*)d_in[17];
    const float* w_pr   = (const float*)d_in[18];
    const float* b_pr   = (const float*)d_in[19];
    const float* lnf_g  = (const float*)d_in[20];
    const float* lnf_b  = (const float*)d_in[21];

    float* tembBuf = (float*)d_ws;                                   // 32 KB
    unsigned short* frags = (unsigned short*)((char*)d_ws + 32768);  // 96 KB

    pack_frags<<<96, 512, 0, stream>>>(w_qkv, w_o, w_fc, w_pr, frags);
    temb_precompute<<<128, 256, 0, stream>>>(nloops, t_w1, t_b1, t_w2, t_b2, tembBuf);
    looped_tf<<<BB, NTHR, 0, stream>>>(idx, nloops, wte, wpe, ln1_g, ln1_b,
                                       b_qkv, b_o, ln2_g, ln2_b,
                                       b_fc, b_pr, lnf_g, lnf_b,
                                       tembBuf, frags, (float*)d_out);
}